// Round 6
// baseline (505.430 us; speedup 1.0000x reference)
//
#include <hip/hip_runtime.h>
#include <hip/hip_bf16.h>
#include <hip/hip_fp16.h>

#define N_ 50000
#define E_ 800000
#define D_ 128
#define L_ 3

#define AGG_BLOCKS 625
#define AGG_GPB 5   // node-groups (16 nodes) per block: 625*5*16 = 50000

typedef _Float16 half8 __attribute__((ext_vector_type(8)));
typedef float f32x4 __attribute__((ext_vector_type(4)));

// ---------------- helpers ----------------

__device__ inline unsigned pkh(float a, float b) {  // 2 fp32 -> packed fp16 (RTNE)
    __half2 h = __floats2half2_rn(a, b);
    return *(unsigned*)&h;
}

__device__ inline unsigned short pkh1(float a) {
    _Float16 h = (_Float16)a;
    return *(unsigned short*)&h;
}

__device__ inline float2 h2f2(unsigned u) {
    return __half22float2(*(__half2*)&u);
}

// ---------------- CSR build ----------------

__global__ void k_count(const int* __restrict__ dst, int* __restrict__ deg,
                        int* __restrict__ offbuf) {
    int e = blockIdx.x * 256 + threadIdx.x;
    if (e < E_) offbuf[e] = atomicAdd(&deg[dst[e]], 1);
}

__global__ __launch_bounds__(1024) void k_scan1(const int* __restrict__ deg,
                                                int* __restrict__ linc,
                                                int* __restrict__ bsum,
                                                float* __restrict__ dis) {
    __shared__ int wsum[16];
    int t    = threadIdx.x;
    int lane = t & 63;
    int wid  = t >> 6;
    int i    = blockIdx.x * 1024 + t;
    int d    = (i < N_) ? deg[i] : 0;
    if (i < N_) dis[i] = rsqrtf((float)d + 1.0f);
    int v = d;
#pragma unroll
    for (int off = 1; off < 64; off <<= 1) {
        int u = __shfl_up(v, off);
        if (lane >= off) v += u;
    }
    if (lane == 63) wsum[wid] = v;
    __syncthreads();
    if (wid == 0) {
        int w = (lane < 16) ? wsum[lane] : 0;
#pragma unroll
        for (int off = 1; off < 16; off <<= 1) {
            int u = __shfl_up(w, off);
            if (lane >= off) w += u;
        }
        if (lane < 16) wsum[lane] = w;
    }
    __syncthreads();
    int woff = (wid > 0) ? wsum[wid - 1] : 0;
    v += woff;
    if (i < N_) linc[i] = v;
    if (t == 1023) bsum[blockIdx.x] = v;
}

__global__ void k_scan2(const int* __restrict__ bsum, int* __restrict__ boff) {
    int lane = threadIdx.x;   // 64
    int v = (lane < 49) ? bsum[lane] : 0;
#pragma unroll
    for (int off = 1; off < 64; off <<= 1) {
        int u = __shfl_up(v, off);
        if (lane >= off) v += u;
    }
    if (lane < 49) boff[lane] = v - bsum[lane];
}

__global__ __launch_bounds__(1024) void k_scan3(const int* __restrict__ linc,
                                                const int* __restrict__ boff,
                                                int* __restrict__ row_ptr) {
    int i = blockIdx.x * 1024 + threadIdx.x;
    if (i < N_) row_ptr[i + 1] = linc[i] + boff[blockIdx.x];
    if (i == 0) row_ptr[0] = 0;
}

__global__ void k_fill(const int* __restrict__ src, const int* __restrict__ dst,
                       const int* __restrict__ row_ptr, const int* __restrict__ offbuf,
                       int* __restrict__ csr_src) {
    int e = blockIdx.x * 256 + threadIdx.x;
    if (e < E_) {
        int d = dst[e];
        csr_src[row_ptr[d] + offbuf[e]] = src[e];
    }
}

// ---------------- W precompute: fp32 [k][n] -> fp16 transposed [n][k] ----------------

__global__ __launch_bounds__(256) void k_prew(const float* __restrict__ Ws,
                                              unsigned short* __restrict__ Wb) {
    int l = blockIdx.x;
    const float* Wl = Ws + l * 16384;
    unsigned short* Wo = Wb + l * 16384;
    for (int i = threadIdx.x; i < 16384; i += 256) {
        int n = i >> 7, k = i & 127;
        Wo[n * 128 + k] = pkh1(Wl[k * 128 + n]);
    }
}

// ---------------- MFMA GEMM with fused input-normalize ----------------
// If st != null: x_row = relu(a*Xin + b) (+ res), side-written to xout (fp32); else x = Xin.
// Output: Hb = fp16( dis[row] * (x @ W) ), stored PANEL-MAJOR: Hb[p][N][32], p = f>>5.

__global__ __launch_bounds__(256) void k_gemm(const float* __restrict__ Xin,
                                              const unsigned short* __restrict__ Wb,
                                              const float* __restrict__ dis,
                                              uint4* __restrict__ Hb4,
                                              const float* __restrict__ st,
                                              const float* __restrict__ gamma,
                                              const float* __restrict__ beta,
                                              const float* __restrict__ res,
                                              float* __restrict__ xout) {
    __shared__ unsigned short wt[128 * 136];   // W^T fp16, padded stride 136
    __shared__ unsigned short xb[64 * 136];    // X tile fp16 (reused for C repack)
    __shared__ float sab[256];
    int t  = threadIdx.x;
    int r0 = blockIdx.x * 64;

    if (st) {
        if (t < 128) {
            float s = 0.f, s2 = 0.f;
#pragma unroll
            for (int k = 0; k < 8; ++k) {
                s  += st[k * 256 + t];
                s2 += st[k * 256 + 128 + t];
            }
            float mean = s * (1.0f / N_);
            float var  = s2 * (1.0f / N_) - mean * mean;
            float a = gamma[t] * rsqrtf(var + 1e-5f);
            sab[t]       = a;
            sab[128 + t] = beta[t] - mean * a;
        }
        __syncthreads();
    }

    // stage W^T (2048 uint4, 8 per thread, coalesced)
#pragma unroll
    for (int j = 0; j < 8; ++j) {
        int i = t + 256 * j;
        int row = i >> 4, c16 = i & 15;
        *(uint4*)&wt[row * 136 + c16 * 8] = ((const uint4*)Wb)[i];
    }
    // stage X: fp32 -> (affine/relu/res) -> fp16 LDS (+ fp32 side-write)
#pragma unroll
    for (int j = 0; j < 8; ++j) {
        int g   = t + 256 * j;          // float4 index among 64*32
        int row = g >> 5;
        int c4  = (g & 31) * 4;
        int gr  = r0 + row;
        float4 v = make_float4(0.f, 0.f, 0.f, 0.f);
        if (gr < N_) {
            v = *(const float4*)(Xin + gr * 128 + c4);
            if (st) {
                v.x = fmaxf(sab[c4] * v.x + sab[128 + c4], 0.f);
                v.y = fmaxf(sab[c4 + 1] * v.y + sab[128 + c4 + 1], 0.f);
                v.z = fmaxf(sab[c4 + 2] * v.z + sab[128 + c4 + 2], 0.f);
                v.w = fmaxf(sab[c4 + 3] * v.w + sab[128 + c4 + 3], 0.f);
                if (res) {
                    float4 rr = *(const float4*)(res + gr * 128 + c4);
                    v.x += rr.x; v.y += rr.y; v.z += rr.z; v.w += rr.w;
                }
                *(float4*)(xout + gr * 128 + c4) = v;
            }
        }
        uint2 p;
        p.x = pkh(v.x, v.y);
        p.y = pkh(v.z, v.w);
        *(uint2*)&xb[row * 136 + c4] = p;
    }
    __syncthreads();

    int wv   = t >> 6;
    int lane = t & 63;
    int ln   = lane & 15;
    int quad = lane >> 4;

    const unsigned short* arow = &xb[(wv * 16 + ln) * 136 + quad * 8];
    half8 af[4];
#pragma unroll
    for (int ks = 0; ks < 4; ++ks) af[ks] = *(const half8*)(arow + ks * 32);

    f32x4 acc[8];
#pragma unroll
    for (int ct = 0; ct < 8; ++ct) acc[ct] = (f32x4){0.f, 0.f, 0.f, 0.f};

#pragma unroll
    for (int ct = 0; ct < 8; ++ct) {
        const unsigned short* wp = &wt[(ct * 16 + ln) * 136 + quad * 8];
#pragma unroll
        for (int ks = 0; ks < 4; ++ks) {
            half8 bf = *(const half8*)(wp + ks * 32);
            acc[ct] = __builtin_amdgcn_mfma_f32_16x16x32_f16(af[ks], bf, acc[ct], 0, 0, 0);
        }
    }

    // epilogue: dis-scale, fp16, repack via LDS (xb reused)
    float dr[4];
#pragma unroll
    for (int reg = 0; reg < 4; ++reg) {
        int r = r0 + wv * 16 + quad * 4 + reg;
        dr[reg] = dis[r < N_ ? r : (N_ - 1)];
    }
    __syncthreads();   // xb reuse
#pragma unroll
    for (int ct = 0; ct < 8; ++ct) {
#pragma unroll
        for (int reg = 0; reg < 4; ++reg) {
            int lrow = wv * 16 + quad * 4 + reg;
            xb[lrow * 136 + ct * 16 + ln] = pkh1(acc[ct][reg] * dr[reg]);
        }
    }
    __syncthreads();
    // panel-major store: Hb4[pan*N*4 + row*4 + q]  (4 KB contiguous per j, coalesced)
#pragma unroll
    for (int j = 0; j < 4; ++j) {
        int n_local = t >> 2;
        int q = t & 3;
        int gr = r0 + n_local;
        if (gr < N_)
            Hb4[j * (N_ * 4) + gr * 4 + q] = *(uint4*)&xb[n_local * 136 + j * 32 + q * 8];
    }
}

// ---------------- Aggregation + fused BN stats: panel-swept ----------------
// 625 blocks (whole grid co-resident) x 5 groups x 16 nodes; panel loop outermost
// so the entire chip gathers from one 3.2 MB (L2-resident) panel at a time.

__global__ __launch_bounds__(256) void k_agg(const unsigned* __restrict__ Hu,
                                             const int* __restrict__ row_ptr,
                                             const int* __restrict__ csr_src,
                                             const float* __restrict__ dis,
                                             const float* __restrict__ bias,
                                             float2* __restrict__ AGG,
                                             float* __restrict__ stats2) {
    int tid  = threadIdx.x;
    int sub  = tid >> 4;          // 0..15 node in group
    int lane = tid & 15;          // 2 features within panel

    float st_[4][4];              // [panel][sx, sx2, sy, sy2]
#pragma unroll
    for (int p = 0; p < 4; ++p)
#pragma unroll
        for (int i = 0; i < 4; ++i) st_[p][i] = 0.f;

#pragma unroll
    for (int p = 0; p < 4; ++p) {
        const unsigned* Hp = Hu + p * (N_ * 16);
        for (int gi = 0; gi < AGG_GPB; ++gi) {
            int g    = gi * AGG_BLOCKS + blockIdx.x;
            int node = g * 16 + sub;
            int beg = row_ptr[node], end = row_ptr[node + 1];
            float2 acc = h2f2(Hp[node * 16 + lane]);   // self term (dis-scaled)

            for (int c = beg; c < end; c += 16) {
                int m = end - c; if (m > 16) m = 16;
                int idx = (lane < m) ? csr_src[c + lane] : 0;
                int j = 0;
                for (; j + 4 <= m; j += 4) {
                    int s0 = __shfl(idx, j, 16);
                    int s1 = __shfl(idx, j + 1, 16);
                    int s2 = __shfl(idx, j + 2, 16);
                    int s3 = __shfl(idx, j + 3, 16);
                    unsigned u0 = Hp[s0 * 16 + lane];
                    unsigned u1 = Hp[s1 * 16 + lane];
                    unsigned u2 = Hp[s2 * 16 + lane];
                    unsigned u3 = Hp[s3 * 16 + lane];
                    float2 f0 = h2f2(u0), f1 = h2f2(u1), f2 = h2f2(u2), f3 = h2f2(u3);
                    acc.x += f0.x + f1.x + f2.x + f3.x;
                    acc.y += f0.y + f1.y + f2.y + f3.y;
                }
                for (; j < m; ++j) {
                    int s0 = __shfl(idx, j, 16);
                    float2 f0 = h2f2(Hp[s0 * 16 + lane]);
                    acc.x += f0.x; acc.y += f0.y;
                }
            }

            float dn = dis[node];
            int f0 = p * 32 + lane * 2;
            float2 b2 = *(const float2*)(bias + f0);
            float2 r;
            r.x = dn * acc.x + b2.x;
            r.y = dn * acc.y + b2.y;
            AGG[node * 64 + p * 16 + lane] = r;
            st_[p][0] += r.x; st_[p][1] += r.x * r.x;
            st_[p][2] += r.y; st_[p][3] += r.y * r.y;
        }
    }

    // end-of-kernel stats reduction: sub dimension via LDS, 8-spread global atomics
    __shared__ float red[16][64];
    float* stp = stats2 + (blockIdx.x & 7) * 256;
#pragma unroll
    for (int p = 0; p < 4; ++p) {
        *(float4*)&red[sub][lane * 4] =
            make_float4(st_[p][0], st_[p][1], st_[p][2], st_[p][3]);
        __syncthreads();
        if (tid < 64) {
            int lane2 = tid >> 2, slot = tid & 3;
            float s = 0.f;
#pragma unroll
            for (int k = 0; k < 16; ++k) s += red[k][tid];
            int f = p * 32 + lane2 * 2 + (slot >> 1);
            atomicAdd(&stp[(slot & 1) * 128 + f], s);
        }
        __syncthreads();
    }
}

// ---------------- Final normalize (layer 2): out = res + affine(AGG) ----------------

__global__ __launch_bounds__(256) void k_normF(const float4* __restrict__ AGG,
                                               const float4* __restrict__ res,
                                               const float* __restrict__ st,
                                               const float* __restrict__ gamma,
                                               const float* __restrict__ beta,
                                               float4* __restrict__ OUT) {
    __shared__ float sab[256];
    int t = threadIdx.x;
    if (t < 128) {
        float s = 0.f, s2 = 0.f;
#pragma unroll
        for (int k = 0; k < 8; ++k) {
            s  += st[k * 256 + t];
            s2 += st[k * 256 + 128 + t];
        }
        float mean = s * (1.0f / N_);
        float var  = s2 * (1.0f / N_) - mean * mean;
        float a = gamma[t] * rsqrtf(var + 1e-5f);
        sab[t]       = a;
        sab[128 + t] = beta[t] - mean * a;
    }
    __syncthreads();
    for (int i = blockIdx.x * 256 + t; i < N_ * 32; i += gridDim.x * 256) {
        int f4 = (i & 31) * 4;
        float4 v = AGG[i];
        float4 rr = res[i];
        v.x = sab[f4] * v.x + sab[128 + f4] + rr.x;
        v.y = sab[f4 + 1] * v.y + sab[128 + f4 + 1] + rr.y;
        v.z = sab[f4 + 2] * v.z + sab[128 + f4 + 2] + rr.z;
        v.w = sab[f4 + 3] * v.w + sab[128 + f4 + 3] + rr.w;
        OUT[i] = v;
    }
}

// ---------------- Launch ----------------

extern "C" void kernel_launch(void* const* d_in, const int* in_sizes, int n_in,
                              void* d_out, int out_size, void* d_ws, size_t ws_size,
                              hipStream_t stream) {
    const float* x      = (const float*)d_in[0];
    const int*   ei     = (const int*)d_in[1];
    const float* Ws     = (const float*)d_in[2];
    const float* bs     = (const float*)d_in[3];
    const float* gammas = (const float*)d_in[4];
    const float* betas  = (const float*)d_in[5];
    float* out = (float*)d_out;

    const int* src = ei;
    const int* dst = ei + E_;

    char* w = (char*)d_ws;
    int*   deg     = (int*)(w + 0);            // N ints            [0, 200000)
    float* stats2  = (float*)(w + 200000);     // 3*2048 floats     [200000, 224576)
    int*   row_ptr = (int*)(w + 224576);       // N+1 ints          [224576, 424592)
    float* dis     = (float*)(w + 424592);     // N floats          [424592, 624592)
    int*   offbuf  = (int*)(w + 624592);       // E ints            [624592, 3824592)  (dead after k_fill)
    int*   csr_src = (int*)(w + 3824592);      // E ints            [3824592, 7024592)
    uint4* Hb4     = (uint4*)(w + 7024640);    // N*D fp16 panel-major 12.8 MB
    float* XB      = (float*)(w + 19824640);   // N*D fp32 25.6 MB
    unsigned short* Wb = (unsigned short*)offbuf;  // 3*128*128 fp16, reuses dead offbuf
    float* AGG     = out;                      // AGG lives in d_out

    // scan scratch reuses XB (dead until layer loop)
    int* linc = (int*)XB;
    int* bsum = (int*)XB + N_;
    int* boff = (int*)XB + N_ + 64;

    hipMemsetAsync(d_ws, 0, 224576, stream);   // deg + stats2

    k_count<<<(E_ + 255) / 256, 256, 0, stream>>>(dst, deg, offbuf);
    k_scan1<<<49, 1024, 0, stream>>>(deg, linc, bsum, dis);
    k_scan2<<<1, 64, 0, stream>>>(bsum, boff);
    k_scan3<<<49, 1024, 0, stream>>>(linc, boff, row_ptr);
    k_fill<<<(E_ + 255) / 256, 256, 0, stream>>>(src, dst, row_ptr, offbuf, csr_src);
    k_prew<<<3, 256, 0, stream>>>(Ws, Wb);     // offbuf dead after k_fill

    const int GG = (N_ + 63) / 64;   // 782
    // L0: gemm(x raw) -> Hb ; agg -> AGG(d_out), st0
    k_gemm<<<GG, 256, 0, stream>>>(x, Wb, dis, Hb4,
                                   nullptr, nullptr, nullptr, nullptr, nullptr);
    k_agg<<<AGG_BLOCKS, 256, 0, stream>>>((const unsigned*)Hb4, row_ptr, csr_src, dis,
                                          bs, (float2*)AGG, stats2);
    // L1: gemm(AGG0 | affine0+relu -> x1 -> XB) -> Hb ; agg -> AGG, st1
    k_gemm<<<GG, 256, 0, stream>>>(AGG, Wb + 16384, dis, Hb4,
                                   stats2, gammas, betas, nullptr, XB);
    k_agg<<<AGG_BLOCKS, 256, 0, stream>>>((const unsigned*)Hb4, row_ptr, csr_src, dis,
                                          bs + D_, (float2*)AGG, stats2 + 2048);
    // L2: gemm(AGG1 | affine1+relu + res XB -> x2 -> XB) -> Hb ; agg -> AGG, st2
    k_gemm<<<GG, 256, 0, stream>>>(AGG, Wb + 32768, dis, Hb4,
                                   stats2 + 2048, gammas + D_, betas + D_, XB, XB);
    k_agg<<<AGG_BLOCKS, 256, 0, stream>>>((const unsigned*)Hb4, row_ptr, csr_src, dis,
                                          bs + 2 * D_, (float2*)AGG, stats2 + 4096);
    // final: out = x2 + affine2(AGG2)   (in-place on d_out)
    k_normF<<<512, 256, 0, stream>>>((const float4*)AGG, (const float4*)XB,
                                     stats2 + 4096, gammas + 2 * D_, betas + 2 * D_,
                                     (float4*)out);
}

// Round 7
// 451.608 us; speedup vs baseline: 1.1192x; 1.1192x over previous
//
#include <hip/hip_runtime.h>
#include <hip/hip_bf16.h>
#include <hip/hip_fp16.h>

#define N_ 50000
#define E_ 800000
#define D_ 128
#define L_ 3

typedef _Float16 half8 __attribute__((ext_vector_type(8)));
typedef float f32x4 __attribute__((ext_vector_type(4)));

// ---------------- helpers ----------------

__device__ inline float4 hcvt(uint2 u) {   // 4 packed fp16 -> float4
    __half2 h0 = *(__half2*)&u.x;
    __half2 h1 = *(__half2*)&u.y;
    float2 f0 = __half22float2(h0);
    float2 f1 = __half22float2(h1);
    return make_float4(f0.x, f0.y, f1.x, f1.y);
}

__device__ inline unsigned pkh(float a, float b) {  // 2 fp32 -> packed fp16 (RTNE)
    __half2 h = __floats2half2_rn(a, b);
    return *(unsigned*)&h;
}

__device__ inline unsigned short pkh1(float a) {
    _Float16 h = (_Float16)a;
    return *(unsigned short*)&h;
}

// ---------------- CSR build ----------------

__global__ void k_count(const int* __restrict__ dst, int* __restrict__ deg,
                        int* __restrict__ offbuf) {
    int e = blockIdx.x * 256 + threadIdx.x;
    if (e < E_) offbuf[e] = atomicAdd(&deg[dst[e]], 1);
}

// degree histogram (64 bins, deg clamped to 63)
__global__ void k_hist(const int* __restrict__ deg, int* __restrict__ hist) {
    __shared__ int lh[64];
    if (threadIdx.x < 64) lh[threadIdx.x] = 0;
    __syncthreads();
    int i = blockIdx.x * 256 + threadIdx.x;
    if (i < N_) atomicAdd(&lh[min(deg[i], 63)], 1);
    __syncthreads();
    if (threadIdx.x < 64 && lh[threadIdx.x]) atomicAdd(&hist[threadIdx.x], lh[threadIdx.x]);
}

__global__ void k_hscan(const int* __restrict__ hist, int* __restrict__ hoff) {
    int lane = threadIdx.x;   // 64
    int v = hist[lane];
    int s = v;
#pragma unroll
    for (int off = 1; off < 64; off <<= 1) {
        int u = __shfl_up(s, off);
        if (lane >= off) s += u;
    }
    hoff[lane] = s - v;   // exclusive
}

// scatter node ids into degree-sorted order (hoff used as live cursors)
__global__ void k_order(const int* __restrict__ deg, int* __restrict__ hoff,
                        int* __restrict__ order) {
    int i = blockIdx.x * 256 + threadIdx.x;
    if (i < N_) {
        int pos = atomicAdd(&hoff[min(deg[i], 63)], 1);
        order[pos] = i;
    }
}

__global__ __launch_bounds__(1024) void k_scan1(const int* __restrict__ deg,
                                                int* __restrict__ linc,
                                                int* __restrict__ bsum,
                                                float* __restrict__ dis) {
    __shared__ int wsum[16];
    int t    = threadIdx.x;
    int lane = t & 63;
    int wid  = t >> 6;
    int i    = blockIdx.x * 1024 + t;
    int d    = (i < N_) ? deg[i] : 0;
    if (i < N_) dis[i] = rsqrtf((float)d + 1.0f);
    int v = d;
#pragma unroll
    for (int off = 1; off < 64; off <<= 1) {
        int u = __shfl_up(v, off);
        if (lane >= off) v += u;
    }
    if (lane == 63) wsum[wid] = v;
    __syncthreads();
    if (wid == 0) {
        int w = (lane < 16) ? wsum[lane] : 0;
#pragma unroll
        for (int off = 1; off < 16; off <<= 1) {
            int u = __shfl_up(w, off);
            if (lane >= off) w += u;
        }
        if (lane < 16) wsum[lane] = w;
    }
    __syncthreads();
    int woff = (wid > 0) ? wsum[wid - 1] : 0;
    v += woff;
    if (i < N_) linc[i] = v;
    if (t == 1023) bsum[blockIdx.x] = v;
}

__global__ void k_scan2(const int* __restrict__ bsum, int* __restrict__ boff) {
    int lane = threadIdx.x;   // 64
    int v = (lane < 49) ? bsum[lane] : 0;
#pragma unroll
    for (int off = 1; off < 64; off <<= 1) {
        int u = __shfl_up(v, off);
        if (lane >= off) v += u;
    }
    if (lane < 49) boff[lane] = v - bsum[lane];
}

__global__ __launch_bounds__(1024) void k_scan3(const int* __restrict__ linc,
                                                const int* __restrict__ boff,
                                                int* __restrict__ row_ptr) {
    int i = blockIdx.x * 1024 + threadIdx.x;
    if (i < N_) row_ptr[i + 1] = linc[i] + boff[blockIdx.x];
    if (i == 0) row_ptr[0] = 0;
}

__global__ void k_fill(const int* __restrict__ src, const int* __restrict__ dst,
                       const int* __restrict__ row_ptr, const int* __restrict__ offbuf,
                       int* __restrict__ csr_src) {
    int e = blockIdx.x * 256 + threadIdx.x;
    if (e < E_) {
        int d = dst[e];
        csr_src[row_ptr[d] + offbuf[e]] = src[e];
    }
}

// ---------------- W precompute: fp32 [k][n] -> fp16 transposed [n][k] ----------------

__global__ __launch_bounds__(256) void k_prew(const float* __restrict__ Ws,
                                              unsigned short* __restrict__ Wb) {
    int l = blockIdx.x;
    const float* Wl = Ws + l * 16384;
    unsigned short* Wo = Wb + l * 16384;
    for (int i = threadIdx.x; i < 16384; i += 256) {
        int n = i >> 7, k = i & 127;
        Wo[n * 128 + k] = pkh1(Wl[k * 128 + n]);
    }
}

// ---------------- MFMA GEMM with fused input-normalize ----------------
// If st != null: x_row = relu(a*Xin + b) (+ res), side-written to xout (fp32); else x = Xin.
// Output: Hb = fp16( dis[row] * (x @ W) ), row-major [N][128].

__global__ __launch_bounds__(256) void k_gemm(const float* __restrict__ Xin,
                                              const unsigned short* __restrict__ Wb,
                                              const float* __restrict__ dis,
                                              uint4* __restrict__ Hb,
                                              const float* __restrict__ st,
                                              const float* __restrict__ gamma,
                                              const float* __restrict__ beta,
                                              const float* __restrict__ res,
                                              float* __restrict__ xout) {
    __shared__ unsigned short wt[128 * 136];   // W^T fp16, padded stride 136
    __shared__ unsigned short xb[64 * 136];    // X tile fp16 (reused for C repack)
    __shared__ float sab[256];
    int t  = threadIdx.x;
    int r0 = blockIdx.x * 64;

    if (st) {
        if (t < 128) {
            float s = 0.f, s2 = 0.f;
#pragma unroll
            for (int k = 0; k < 8; ++k) {
                s  += st[k * 256 + t];
                s2 += st[k * 256 + 128 + t];
            }
            float mean = s * (1.0f / N_);
            float var  = s2 * (1.0f / N_) - mean * mean;
            float a = gamma[t] * rsqrtf(var + 1e-5f);
            sab[t]       = a;
            sab[128 + t] = beta[t] - mean * a;
        }
        __syncthreads();
    }

    // stage W^T (2048 uint4, 8 per thread, coalesced)
#pragma unroll
    for (int j = 0; j < 8; ++j) {
        int i = t + 256 * j;
        int row = i >> 4, c16 = i & 15;
        *(uint4*)&wt[row * 136 + c16 * 8] = ((const uint4*)Wb)[i];
    }
    // stage X: fp32 -> (affine/relu/res) -> fp16 LDS (+ fp32 side-write)
#pragma unroll
    for (int j = 0; j < 8; ++j) {
        int g   = t + 256 * j;          // float4 index among 64*32
        int row = g >> 5;
        int c4  = (g & 31) * 4;
        int gr  = r0 + row;
        float4 v = make_float4(0.f, 0.f, 0.f, 0.f);
        if (gr < N_) {
            v = *(const float4*)(Xin + gr * 128 + c4);
            if (st) {
                v.x = fmaxf(sab[c4] * v.x + sab[128 + c4], 0.f);
                v.y = fmaxf(sab[c4 + 1] * v.y + sab[128 + c4 + 1], 0.f);
                v.z = fmaxf(sab[c4 + 2] * v.z + sab[128 + c4 + 2], 0.f);
                v.w = fmaxf(sab[c4 + 3] * v.w + sab[128 + c4 + 3], 0.f);
                if (res) {
                    float4 rr = *(const float4*)(res + gr * 128 + c4);
                    v.x += rr.x; v.y += rr.y; v.z += rr.z; v.w += rr.w;
                }
                *(float4*)(xout + gr * 128 + c4) = v;
            }
        }
        uint2 p;
        p.x = pkh(v.x, v.y);
        p.y = pkh(v.z, v.w);
        *(uint2*)&xb[row * 136 + c4] = p;
    }
    __syncthreads();

    int wv   = t >> 6;
    int lane = t & 63;
    int ln   = lane & 15;
    int quad = lane >> 4;

    const unsigned short* arow = &xb[(wv * 16 + ln) * 136 + quad * 8];
    half8 af[4];
#pragma unroll
    for (int ks = 0; ks < 4; ++ks) af[ks] = *(const half8*)(arow + ks * 32);

    f32x4 acc[8];
#pragma unroll
    for (int ct = 0; ct < 8; ++ct) acc[ct] = (f32x4){0.f, 0.f, 0.f, 0.f};

#pragma unroll
    for (int ct = 0; ct < 8; ++ct) {
        const unsigned short* wp = &wt[(ct * 16 + ln) * 136 + quad * 8];
#pragma unroll
        for (int ks = 0; ks < 4; ++ks) {
            half8 bf = *(const half8*)(wp + ks * 32);
            acc[ct] = __builtin_amdgcn_mfma_f32_16x16x32_f16(af[ks], bf, acc[ct], 0, 0, 0);
        }
    }

    // epilogue: dis-scale, fp16, repack via LDS (xb reused), coalesced uint4 store
    float dr[4];
#pragma unroll
    for (int reg = 0; reg < 4; ++reg) {
        int r = r0 + wv * 16 + quad * 4 + reg;
        dr[reg] = dis[r < N_ ? r : (N_ - 1)];
    }
    __syncthreads();   // xb reuse
#pragma unroll
    for (int ct = 0; ct < 8; ++ct) {
#pragma unroll
        for (int reg = 0; reg < 4; ++reg) {
            int lrow = wv * 16 + quad * 4 + reg;
            xb[lrow * 136 + ct * 16 + ln] = pkh1(acc[ct][reg] * dr[reg]);
        }
    }
    __syncthreads();
#pragma unroll
    for (int j = 0; j < 4; ++j) {
        int i = t + 256 * j;       // uint4 among 64*16
        int row = i >> 4, c16 = i & 15;
        int gr = r0 + row;
        if (gr < N_) Hb[gr * 16 + c16] = *(uint4*)&xb[row * 136 + c16 * 8];
    }
}

// ---------------- Aggregation + fused BN stats (degree-sorted order) ----------------
// 16 nodes / 256-thread block via order[]; 16 lanes/node, 8 features (uint4) each.

__global__ __launch_bounds__(256) void k_agg(const uint4* __restrict__ Hb,
                                             const int* __restrict__ row_ptr,
                                             const int* __restrict__ csr_src,
                                             const int* __restrict__ order,
                                             const float* __restrict__ dis,
                                             const float* __restrict__ bias,
                                             float4* __restrict__ AGG,
                                             float* __restrict__ stats2) {
    int tid  = threadIdx.x;
    int sub  = tid >> 4;          // 0..15 node in block
    int lane = tid & 15;          // feature group: 8 feats
    int node = order[blockIdx.x * 16 + sub];

    int beg = row_ptr[node], end = row_ptr[node + 1];
    uint4 su = Hb[node * 16 + lane];
    float4 acc0 = hcvt(make_uint2(su.x, su.y));
    float4 acc1 = hcvt(make_uint2(su.z, su.w));

    for (int c = beg; c < end; c += 16) {
        int m = end - c; if (m > 16) m = 16;
        int idx = (lane < m) ? csr_src[c + lane] : 0;
        int j = 0;
        for (; j + 4 <= m; j += 4) {
            int s0 = __shfl(idx, j, 16);
            int s1 = __shfl(idx, j + 1, 16);
            int s2 = __shfl(idx, j + 2, 16);
            int s3 = __shfl(idx, j + 3, 16);
            uint4 a0 = Hb[s0 * 16 + lane];
            uint4 a1 = Hb[s1 * 16 + lane];
            uint4 a2 = Hb[s2 * 16 + lane];
            uint4 a3 = Hb[s3 * 16 + lane];
            float4 f00 = hcvt(make_uint2(a0.x, a0.y)), f01 = hcvt(make_uint2(a0.z, a0.w));
            float4 f10 = hcvt(make_uint2(a1.x, a1.y)), f11 = hcvt(make_uint2(a1.z, a1.w));
            float4 f20 = hcvt(make_uint2(a2.x, a2.y)), f21 = hcvt(make_uint2(a2.z, a2.w));
            float4 f30 = hcvt(make_uint2(a3.x, a3.y)), f31 = hcvt(make_uint2(a3.z, a3.w));
            acc0.x += f00.x + f10.x + f20.x + f30.x;
            acc0.y += f00.y + f10.y + f20.y + f30.y;
            acc0.z += f00.z + f10.z + f20.z + f30.z;
            acc0.w += f00.w + f10.w + f20.w + f30.w;
            acc1.x += f01.x + f11.x + f21.x + f31.x;
            acc1.y += f01.y + f11.y + f21.y + f31.y;
            acc1.z += f01.z + f11.z + f21.z + f31.z;
            acc1.w += f01.w + f11.w + f21.w + f31.w;
        }
        for (; j < m; ++j) {
            int s0 = __shfl(idx, j, 16);
            uint4 a0 = Hb[s0 * 16 + lane];
            float4 f00 = hcvt(make_uint2(a0.x, a0.y)), f01 = hcvt(make_uint2(a0.z, a0.w));
            acc0.x += f00.x; acc0.y += f00.y; acc0.z += f00.z; acc0.w += f00.w;
            acc1.x += f01.x; acc1.y += f01.y; acc1.z += f01.z; acc1.w += f01.w;
        }
    }

    float dn = dis[node];
    float4 b0 = *(const float4*)(bias + lane * 8);
    float4 b1 = *(const float4*)(bias + lane * 8 + 4);
    float4 r0, r1;
    r0.x = dn * acc0.x + b0.x; r0.y = dn * acc0.y + b0.y;
    r0.z = dn * acc0.z + b0.z; r0.w = dn * acc0.w + b0.w;
    r1.x = dn * acc1.x + b1.x; r1.y = dn * acc1.y + b1.y;
    r1.z = dn * acc1.z + b1.z; r1.w = dn * acc1.w + b1.w;
    AGG[node * 32 + lane * 2]     = r0;
    AGG[node * 32 + lane * 2 + 1] = r1;

    __shared__ float sbuf[16][128];
    float4* sp = (float4*)&sbuf[sub][lane * 8];
    sp[0] = r0; sp[1] = r1;
    __syncthreads();
    if (tid < 128) {
        float s = 0.f, s2 = 0.f;
#pragma unroll
        for (int k = 0; k < 16; ++k) {
            float v = sbuf[k][tid];
            s += v; s2 += v * v;
        }
        float* stp = stats2 + (blockIdx.x & 7) * 256;
        atomicAdd(&stp[tid], s);
        atomicAdd(&stp[128 + tid], s2);
    }
}

// ---------------- Final normalize (layer 2): out = res + affine(AGG) ----------------

__global__ __launch_bounds__(256) void k_normF(const float4* __restrict__ AGG,
                                               const float4* __restrict__ res,
                                               const float* __restrict__ st,
                                               const float* __restrict__ gamma,
                                               const float* __restrict__ beta,
                                               float4* __restrict__ OUT) {
    __shared__ float sab[256];
    int t = threadIdx.x;
    if (t < 128) {
        float s = 0.f, s2 = 0.f;
#pragma unroll
        for (int k = 0; k < 8; ++k) {
            s  += st[k * 256 + t];
            s2 += st[k * 256 + 128 + t];
        }
        float mean = s * (1.0f / N_);
        float var  = s2 * (1.0f / N_) - mean * mean;
        float a = gamma[t] * rsqrtf(var + 1e-5f);
        sab[t]       = a;
        sab[128 + t] = beta[t] - mean * a;
    }
    __syncthreads();
    for (int i = blockIdx.x * 256 + t; i < N_ * 32; i += gridDim.x * 256) {
        int f4 = (i & 31) * 4;
        float4 v = AGG[i];
        float4 rr = res[i];
        v.x = sab[f4] * v.x + sab[128 + f4] + rr.x;
        v.y = sab[f4 + 1] * v.y + sab[128 + f4 + 1] + rr.y;
        v.z = sab[f4 + 2] * v.z + sab[128 + f4 + 2] + rr.z;
        v.w = sab[f4 + 3] * v.w + sab[128 + f4 + 3] + rr.w;
        OUT[i] = v;
    }
}

// ---------------- Launch ----------------

extern "C" void kernel_launch(void* const* d_in, const int* in_sizes, int n_in,
                              void* d_out, int out_size, void* d_ws, size_t ws_size,
                              hipStream_t stream) {
    const float* x      = (const float*)d_in[0];
    const int*   ei     = (const int*)d_in[1];
    const float* Ws     = (const float*)d_in[2];
    const float* bs     = (const float*)d_in[3];
    const float* gammas = (const float*)d_in[4];
    const float* betas  = (const float*)d_in[5];
    float* out = (float*)d_out;

    const int* src = ei;
    const int* dst = ei + E_;

    char* w = (char*)d_ws;
    int*   deg     = (int*)(w + 0);            // N ints            [0, 200000)
    float* stats2  = (float*)(w + 200000);     // 3*2048 floats     [200000, 224576)
    int*   hist    = (int*)(w + 224576);       // 64 ints           [224576, 224832)
    int*   hoff    = (int*)(w + 224832);       // 64 ints           [224832, 225088)
    int*   row_ptr = (int*)(w + 225088);       // N+1 ints          [225088, 425092)
    float* dis     = (float*)(w + 425092);     // N floats          [425092, 625092)
    int*   offbuf  = (int*)(w + 625104);       // E ints            [625104, 3825104)  (dead after k_fill)
    int*   csr_src = (int*)(w + 3825104);      // E ints            [3825104, 7025104)
    uint4* Hb      = (uint4*)(w + 7025104);    // N*D fp16 12.8 MB  [7025104, 19825104)
    float* XB      = (float*)(w + 19825104);   // N*D fp32 25.6 MB  [19825104, 45425104)
    int*   order   = (int*)(w + 45425104);     // N ints            [45425104, 45625104)
    unsigned short* Wb = (unsigned short*)offbuf;  // 3*128*128 fp16, reuses dead offbuf
    float* AGG     = out;                      // AGG lives in d_out

    // scan scratch reuses XB (dead until layer loop)
    int* linc = (int*)XB;
    int* bsum = (int*)XB + N_;
    int* boff = (int*)XB + N_ + 64;

    hipMemsetAsync(d_ws, 0, 225088, stream);   // deg + stats2 + hist + hoff

    k_count<<<(E_ + 255) / 256, 256, 0, stream>>>(dst, deg, offbuf);
    k_hist <<<(N_ + 255) / 256, 256, 0, stream>>>(deg, hist);
    k_hscan<<<1, 64, 0, stream>>>(hist, hoff);
    k_order<<<(N_ + 255) / 256, 256, 0, stream>>>(deg, hoff, order);
    k_scan1<<<49, 1024, 0, stream>>>(deg, linc, bsum, dis);
    k_scan2<<<1, 64, 0, stream>>>(bsum, boff);
    k_scan3<<<49, 1024, 0, stream>>>(linc, boff, row_ptr);
    k_fill<<<(E_ + 255) / 256, 256, 0, stream>>>(src, dst, row_ptr, offbuf, csr_src);
    k_prew<<<3, 256, 0, stream>>>(Ws, Wb);     // offbuf dead after k_fill

    const int GG = (N_ + 63) / 64;   // 782
    // L0: gemm(x raw) -> Hb ; agg -> AGG(d_out), st0
    k_gemm<<<GG, 256, 0, stream>>>(x, Wb, dis, Hb,
                                   nullptr, nullptr, nullptr, nullptr, nullptr);
    k_agg<<<N_ / 16, 256, 0, stream>>>(Hb, row_ptr, csr_src, order, dis, bs,
                                       (float4*)AGG, stats2);
    // L1: gemm(AGG0 | affine0+relu -> x1 -> XB) -> Hb ; agg -> AGG, st1
    k_gemm<<<GG, 256, 0, stream>>>(AGG, Wb + 16384, dis, Hb,
                                   stats2, gammas, betas, nullptr, XB);
    k_agg<<<N_ / 16, 256, 0, stream>>>(Hb, row_ptr, csr_src, order, dis, bs + D_,
                                       (float4*)AGG, stats2 + 2048);
    // L2: gemm(AGG1 | affine1+relu + res XB -> x2 -> XB) -> Hb ; agg -> AGG, st2
    k_gemm<<<GG, 256, 0, stream>>>(AGG, Wb + 32768, dis, Hb,
                                   stats2 + 2048, gammas + D_, betas + D_, XB, XB);
    k_agg<<<N_ / 16, 256, 0, stream>>>(Hb, row_ptr, csr_src, order, dis, bs + 2 * D_,
                                       (float4*)AGG, stats2 + 4096);
    // final: out = x2 + affine2(AGG2)   (in-place on d_out)
    k_normF<<<512, 256, 0, stream>>>((const float4*)AGG, (const float4*)XB,
                                     stats2 + 4096, gammas + 2 * D_, betas + 2 * D_,
                                     (float4*)out);
}

// Round 8
// 303.638 us; speedup vs baseline: 1.6646x; 1.4873x over previous
//
#include <hip/hip_runtime.h>
#include <hip/hip_bf16.h>
#include <hip/hip_fp16.h>

#define N_ 50000
#define E_ 800000
#define D_ 128
#define L_ 3

typedef _Float16 half8 __attribute__((ext_vector_type(8)));
typedef float f32x4 __attribute__((ext_vector_type(4)));

// ---------------- helpers ----------------

__device__ inline float4 hcvt(uint2 u) {   // 4 packed fp16 -> float4
    __half2 h0 = *(__half2*)&u.x;
    __half2 h1 = *(__half2*)&u.y;
    float2 f0 = __half22float2(h0);
    float2 f1 = __half22float2(h1);
    return make_float4(f0.x, f0.y, f1.x, f1.y);
}

__device__ inline unsigned pkh(float a, float b) {  // 2 fp32 -> packed fp16 (RTNE)
    __half2 h = __floats2half2_rn(a, b);
    return *(unsigned*)&h;
}

__device__ inline unsigned short pkh1(float a) {
    _Float16 h = (_Float16)a;
    return *(unsigned short*)&h;
}

// ---------------- CSR build ----------------

__global__ void k_count(const int* __restrict__ dst, int* __restrict__ deg,
                        int* __restrict__ offbuf) {
    int e = blockIdx.x * 256 + threadIdx.x;
    if (e < E_) offbuf[e] = atomicAdd(&deg[dst[e]], 1);
}

// phase 1: per-block (1024 elems) inclusive scan; also writes dis[] and block sums
__global__ __launch_bounds__(1024) void k_scan1(const int* __restrict__ deg,
                                                int* __restrict__ linc,
                                                int* __restrict__ bsum,
                                                float* __restrict__ dis) {
    __shared__ int wsum[16];
    int t    = threadIdx.x;
    int lane = t & 63;
    int wid  = t >> 6;
    int i    = blockIdx.x * 1024 + t;
    int d    = (i < N_) ? deg[i] : 0;
    if (i < N_) dis[i] = rsqrtf((float)d + 1.0f);
    int v = d;
#pragma unroll
    for (int off = 1; off < 64; off <<= 1) {
        int u = __shfl_up(v, off);
        if (lane >= off) v += u;
    }
    if (lane == 63) wsum[wid] = v;
    __syncthreads();
    if (wid == 0) {
        int w = (lane < 16) ? wsum[lane] : 0;
#pragma unroll
        for (int off = 1; off < 16; off <<= 1) {
            int u = __shfl_up(w, off);
            if (lane >= off) w += u;
        }
        if (lane < 16) wsum[lane] = w;
    }
    __syncthreads();
    int woff = (wid > 0) ? wsum[wid - 1] : 0;
    v += woff;
    if (i < N_) linc[i] = v;
    if (t == 1023) bsum[blockIdx.x] = v;
}

// phase 2 (merged scan-of-blocksums + apply): row_ptr[i+1] = linc[i] + excl_sum(bsum[0..blk))
__global__ __launch_bounds__(1024) void k_scan3(const int* __restrict__ linc,
                                                const int* __restrict__ bsum,
                                                int* __restrict__ row_ptr) {
    __shared__ int sboff;
    int t = threadIdx.x;
    if (t < 64) {
        int v = (t < 49) ? bsum[t] : 0;
#pragma unroll
        for (int off = 1; off < 64; off <<= 1) {
            int u = __shfl_up(v, off);
            if (t >= off) v += u;
        }
        int ex = (blockIdx.x == 0) ? 0 : __shfl(v, (int)blockIdx.x - 1, 64);
        if (t == 0) sboff = ex;
    }
    __syncthreads();
    int i = blockIdx.x * 1024 + t;
    if (i < N_) row_ptr[i + 1] = linc[i] + sboff;
    if (i == 0) row_ptr[0] = 0;
}

// atomic-free fill: position was precomputed in k_count
__global__ void k_fill(const int* __restrict__ src, const int* __restrict__ dst,
                       const int* __restrict__ row_ptr, const int* __restrict__ offbuf,
                       int* __restrict__ csr_src) {
    int e = blockIdx.x * 256 + threadIdx.x;
    if (e < E_) {
        int d = dst[e];
        csr_src[row_ptr[d] + offbuf[e]] = src[e];
    }
}

// ---------------- W precompute: fp32 [k][n] -> fp16 transposed [n][k] ----------------

__global__ __launch_bounds__(256) void k_prew(const float* __restrict__ Ws,
                                              unsigned short* __restrict__ Wb) {
    int l = blockIdx.x;
    const float* Wl = Ws + l * 16384;
    unsigned short* Wo = Wb + l * 16384;
    for (int i = threadIdx.x; i < 16384; i += 256) {
        int n = i >> 7, k = i & 127;
        Wo[n * 128 + k] = pkh1(Wl[k * 128 + n]);
    }
}

// ---------------- MFMA GEMM with fused input-normalize ----------------
// If st != null: x_row = relu(a*Xin + b) (+ resH fp16), side-written to xoutH (fp16);
// else x = Xin. Output: Hb = fp16( dis[row] * (x @ W) ), row-major [N][128].

__global__ __launch_bounds__(256) void k_gemm(const float* __restrict__ Xin,
                                              const unsigned short* __restrict__ Wb,
                                              const float* __restrict__ dis,
                                              uint4* __restrict__ Hb,
                                              const float* __restrict__ st,
                                              const float* __restrict__ gamma,
                                              const float* __restrict__ beta,
                                              const unsigned short* __restrict__ resH,
                                              unsigned short* __restrict__ xoutH) {
    __shared__ unsigned short wt[128 * 136];   // W^T fp16, padded stride 136
    __shared__ unsigned short xb[64 * 136];    // X tile fp16 (reused for C repack)
    __shared__ float sab[256];
    int t  = threadIdx.x;
    int r0 = blockIdx.x * 64;

    if (st) {
        if (t < 128) {
            float s = 0.f, s2 = 0.f;
#pragma unroll
            for (int k = 0; k < 8; ++k) {
                s  += st[k * 256 + t];
                s2 += st[k * 256 + 128 + t];
            }
            float mean = s * (1.0f / N_);
            float var  = s2 * (1.0f / N_) - mean * mean;
            float a = gamma[t] * rsqrtf(var + 1e-5f);
            sab[t]       = a;
            sab[128 + t] = beta[t] - mean * a;
        }
        __syncthreads();
    }

    // stage W^T (2048 uint4, 8 per thread, coalesced)
#pragma unroll
    for (int j = 0; j < 8; ++j) {
        int i = t + 256 * j;
        int row = i >> 4, c16 = i & 15;
        *(uint4*)&wt[row * 136 + c16 * 8] = ((const uint4*)Wb)[i];
    }
    // stage X: fp32 -> (affine/relu/res) -> fp16 LDS (+ fp16 side-write)
#pragma unroll
    for (int j = 0; j < 8; ++j) {
        int g   = t + 256 * j;          // float4 index among 64*32
        int row = g >> 5;
        int c4  = (g & 31) * 4;
        int gr  = r0 + row;
        float4 v = make_float4(0.f, 0.f, 0.f, 0.f);
        if (gr < N_) {
            v = *(const float4*)(Xin + gr * 128 + c4);
            if (st) {
                v.x = fmaxf(sab[c4] * v.x + sab[128 + c4], 0.f);
                v.y = fmaxf(sab[c4 + 1] * v.y + sab[128 + c4 + 1], 0.f);
                v.z = fmaxf(sab[c4 + 2] * v.z + sab[128 + c4 + 2], 0.f);
                v.w = fmaxf(sab[c4 + 3] * v.w + sab[128 + c4 + 3], 0.f);
                if (resH) {
                    float4 rr = hcvt(*(const uint2*)(resH + gr * 128 + c4));
                    v.x += rr.x; v.y += rr.y; v.z += rr.z; v.w += rr.w;
                }
            }
        }
        uint2 p;
        p.x = pkh(v.x, v.y);
        p.y = pkh(v.z, v.w);
        if (st && gr < N_) *(uint2*)(xoutH + gr * 128 + c4) = p;
        *(uint2*)&xb[row * 136 + c4] = p;
    }
    __syncthreads();

    int wv   = t >> 6;
    int lane = t & 63;
    int ln   = lane & 15;
    int quad = lane >> 4;

    const unsigned short* arow = &xb[(wv * 16 + ln) * 136 + quad * 8];
    half8 af[4];
#pragma unroll
    for (int ks = 0; ks < 4; ++ks) af[ks] = *(const half8*)(arow + ks * 32);

    f32x4 acc[8];
#pragma unroll
    for (int ct = 0; ct < 8; ++ct) acc[ct] = (f32x4){0.f, 0.f, 0.f, 0.f};

#pragma unroll
    for (int ct = 0; ct < 8; ++ct) {
        const unsigned short* wp = &wt[(ct * 16 + ln) * 136 + quad * 8];
#pragma unroll
        for (int ks = 0; ks < 4; ++ks) {
            half8 bf = *(const half8*)(wp + ks * 32);
            acc[ct] = __builtin_amdgcn_mfma_f32_16x16x32_f16(af[ks], bf, acc[ct], 0, 0, 0);
        }
    }

    // epilogue: dis-scale, fp16, repack via LDS (xb reused), coalesced uint4 store
    float dr[4];
#pragma unroll
    for (int reg = 0; reg < 4; ++reg) {
        int r = r0 + wv * 16 + quad * 4 + reg;
        dr[reg] = dis[r < N_ ? r : (N_ - 1)];
    }
    __syncthreads();   // xb reuse
#pragma unroll
    for (int ct = 0; ct < 8; ++ct) {
#pragma unroll
        for (int reg = 0; reg < 4; ++reg) {
            int lrow = wv * 16 + quad * 4 + reg;
            xb[lrow * 136 + ct * 16 + ln] = pkh1(acc[ct][reg] * dr[reg]);
        }
    }
    __syncthreads();
#pragma unroll
    for (int j = 0; j < 4; ++j) {
        int i = t + 256 * j;       // uint4 among 64*16
        int row = i >> 4, c16 = i & 15;
        int gr = r0 + row;
        if (gr < N_) Hb[gr * 16 + c16] = *(uint4*)&xb[row * 136 + c16 * 8];
    }
}

// ---------------- Aggregation + fused BN stats (fp16 gathers) ----------------
// 16 nodes / 256-thread block (natural order); 16 lanes/node, 8 features (uint4) each.

__global__ __launch_bounds__(256) void k_agg(const uint4* __restrict__ Hb,
                                             const int* __restrict__ row_ptr,
                                             const int* __restrict__ csr_src,
                                             const float* __restrict__ dis,
                                             const float* __restrict__ bias,
                                             float4* __restrict__ AGG,
                                             float* __restrict__ stats2) {
    int tid  = threadIdx.x;
    int sub  = tid >> 4;          // 0..15 node in block
    int lane = tid & 15;          // feature group: 8 feats
    int node = blockIdx.x * 16 + sub;

    int beg = row_ptr[node], end = row_ptr[node + 1];
    uint4 su = Hb[node * 16 + lane];
    float4 acc0 = hcvt(make_uint2(su.x, su.y));
    float4 acc1 = hcvt(make_uint2(su.z, su.w));

    for (int c = beg; c < end; c += 16) {
        int m = end - c; if (m > 16) m = 16;
        int idx = (lane < m) ? csr_src[c + lane] : 0;
        int j = 0;
        for (; j + 4 <= m; j += 4) {
            int s0 = __shfl(idx, j, 16);
            int s1 = __shfl(idx, j + 1, 16);
            int s2 = __shfl(idx, j + 2, 16);
            int s3 = __shfl(idx, j + 3, 16);
            uint4 a0 = Hb[s0 * 16 + lane];
            uint4 a1 = Hb[s1 * 16 + lane];
            uint4 a2 = Hb[s2 * 16 + lane];
            uint4 a3 = Hb[s3 * 16 + lane];
            float4 f00 = hcvt(make_uint2(a0.x, a0.y)), f01 = hcvt(make_uint2(a0.z, a0.w));
            float4 f10 = hcvt(make_uint2(a1.x, a1.y)), f11 = hcvt(make_uint2(a1.z, a1.w));
            float4 f20 = hcvt(make_uint2(a2.x, a2.y)), f21 = hcvt(make_uint2(a2.z, a2.w));
            float4 f30 = hcvt(make_uint2(a3.x, a3.y)), f31 = hcvt(make_uint2(a3.z, a3.w));
            acc0.x += f00.x + f10.x + f20.x + f30.x;
            acc0.y += f00.y + f10.y + f20.y + f30.y;
            acc0.z += f00.z + f10.z + f20.z + f30.z;
            acc0.w += f00.w + f10.w + f20.w + f30.w;
            acc1.x += f01.x + f11.x + f21.x + f31.x;
            acc1.y += f01.y + f11.y + f21.y + f31.y;
            acc1.z += f01.z + f11.z + f21.z + f31.z;
            acc1.w += f01.w + f11.w + f21.w + f31.w;
        }
        for (; j < m; ++j) {
            int s0 = __shfl(idx, j, 16);
            uint4 a0 = Hb[s0 * 16 + lane];
            float4 f00 = hcvt(make_uint2(a0.x, a0.y)), f01 = hcvt(make_uint2(a0.z, a0.w));
            acc0.x += f00.x; acc0.y += f00.y; acc0.z += f00.z; acc0.w += f00.w;
            acc1.x += f01.x; acc1.y += f01.y; acc1.z += f01.z; acc1.w += f01.w;
        }
    }

    float dn = dis[node];
    float4 b0 = *(const float4*)(bias + lane * 8);
    float4 b1 = *(const float4*)(bias + lane * 8 + 4);
    float4 r0, r1;
    r0.x = dn * acc0.x + b0.x; r0.y = dn * acc0.y + b0.y;
    r0.z = dn * acc0.z + b0.z; r0.w = dn * acc0.w + b0.w;
    r1.x = dn * acc1.x + b1.x; r1.y = dn * acc1.y + b1.y;
    r1.z = dn * acc1.z + b1.z; r1.w = dn * acc1.w + b1.w;
    AGG[node * 32 + lane * 2]     = r0;
    AGG[node * 32 + lane * 2 + 1] = r1;

    __shared__ float sbuf[16][128];
    float4* sp = (float4*)&sbuf[sub][lane * 8];
    sp[0] = r0; sp[1] = r1;
    __syncthreads();
    if (tid < 128) {
        float s = 0.f, s2 = 0.f;
#pragma unroll
        for (int k = 0; k < 16; ++k) {
            float v = sbuf[k][tid];
            s += v; s2 += v * v;
        }
        float* stp = stats2 + (blockIdx.x & 7) * 256;
        atomicAdd(&stp[tid], s);
        atomicAdd(&stp[128 + tid], s2);
    }
}

// ---------------- Final normalize (layer 2): out = resH + affine(AGG) ----------------

__global__ __launch_bounds__(256) void k_normF(const float4* __restrict__ AGG,
                                               const unsigned short* __restrict__ resH,
                                               const float* __restrict__ st,
                                               const float* __restrict__ gamma,
                                               const float* __restrict__ beta,
                                               float4* __restrict__ OUT) {
    __shared__ float sab[256];
    int t = threadIdx.x;
    if (t < 128) {
        float s = 0.f, s2 = 0.f;
#pragma unroll
        for (int k = 0; k < 8; ++k) {
            s  += st[k * 256 + t];
            s2 += st[k * 256 + 128 + t];
        }
        float mean = s * (1.0f / N_);
        float var  = s2 * (1.0f / N_) - mean * mean;
        float a = gamma[t] * rsqrtf(var + 1e-5f);
        sab[t]       = a;
        sab[128 + t] = beta[t] - mean * a;
    }
    __syncthreads();
    for (int i = blockIdx.x * 256 + t; i < N_ * 32; i += gridDim.x * 256) {
        int f4 = (i & 31) * 4;
        float4 v = AGG[i];
        float4 rr = hcvt(((const uint2*)resH)[i]);
        v.x = sab[f4] * v.x + sab[128 + f4] + rr.x;
        v.y = sab[f4 + 1] * v.y + sab[128 + f4 + 1] + rr.y;
        v.z = sab[f4 + 2] * v.z + sab[128 + f4 + 2] + rr.z;
        v.w = sab[f4 + 3] * v.w + sab[128 + f4 + 3] + rr.w;
        OUT[i] = v;
    }
}

// ---------------- Launch ----------------

extern "C" void kernel_launch(void* const* d_in, const int* in_sizes, int n_in,
                              void* d_out, int out_size, void* d_ws, size_t ws_size,
                              hipStream_t stream) {
    const float* x      = (const float*)d_in[0];
    const int*   ei     = (const int*)d_in[1];
    const float* Ws     = (const float*)d_in[2];
    const float* bs     = (const float*)d_in[3];
    const float* gammas = (const float*)d_in[4];
    const float* betas  = (const float*)d_in[5];
    float* out = (float*)d_out;

    const int* src = ei;
    const int* dst = ei + E_;

    char* w = (char*)d_ws;
    int*   deg     = (int*)(w + 0);            // N ints            [0, 200000)
    float* stats2  = (float*)(w + 200000);     // 3*2048 floats     [200000, 224576)
    int*   row_ptr = (int*)(w + 224576);       // N+1 ints          [224576, 424592)
    float* dis     = (float*)(w + 424592);     // N floats          [424592, 624592)
    int*   offbuf  = (int*)(w + 624592);       // E ints            [624592, 3824592)  (dead after k_fill)
    int*   csr_src = (int*)(w + 3824592);      // E ints            [3824592, 7024592)
    uint4* Hb      = (uint4*)(w + 7024640);    // N*D fp16 12.8 MB  [7024640, 19824640)
    unsigned short* XBh = (unsigned short*)(w + 19824640);  // N*D fp16 12.8 MB
    unsigned short* Wb  = (unsigned short*)offbuf;  // 3*128*128 fp16, reuses dead offbuf
    float* AGG     = out;                      // AGG lives in d_out

    // scan scratch reuses XBh (dead until layer loop)
    int* linc = (int*)XBh;          // N ints
    int* bsum = (int*)XBh + N_;     // 49 ints

    hipMemsetAsync(d_ws, 0, 224576, stream);   // deg + stats2

    k_count<<<(E_ + 255) / 256, 256, 0, stream>>>(dst, deg, offbuf);
    k_scan1<<<49, 1024, 0, stream>>>(deg, linc, bsum, dis);
    k_scan3<<<49, 1024, 0, stream>>>(linc, bsum, row_ptr);
    k_fill<<<(E_ + 255) / 256, 256, 0, stream>>>(src, dst, row_ptr, offbuf, csr_src);
    k_prew<<<3, 256, 0, stream>>>(Ws, Wb);     // offbuf dead after k_fill

    const int GG = (N_ + 63) / 64;   // 782
    // L0: gemm(x raw) -> Hb ; agg -> AGG(d_out), st0
    k_gemm<<<GG, 256, 0, stream>>>(x, Wb, dis, Hb,
                                   nullptr, nullptr, nullptr, nullptr, nullptr);
    k_agg<<<N_ / 16, 256, 0, stream>>>(Hb, row_ptr, csr_src, dis, bs,
                                       (float4*)AGG, stats2);
    // L1: gemm(AGG0 | affine0+relu -> x1 -> XBh) -> Hb ; agg -> AGG, st1
    k_gemm<<<GG, 256, 0, stream>>>(AGG, Wb + 16384, dis, Hb,
                                   stats2, gammas, betas, nullptr, XBh);
    k_agg<<<N_ / 16, 256, 0, stream>>>(Hb, row_ptr, csr_src, dis, bs + D_,
                                       (float4*)AGG, stats2 + 2048);
    // L2: gemm(AGG1 | affine1+relu + res XBh -> x2 -> XBh) -> Hb ; agg -> AGG, st2
    k_gemm<<<GG, 256, 0, stream>>>(AGG, Wb + 32768, dis, Hb,
                                   stats2 + 2048, gammas + D_, betas + D_, XBh, XBh);
    k_agg<<<N_ / 16, 256, 0, stream>>>(Hb, row_ptr, csr_src, dis, bs + 2 * D_,
                                       (float4*)AGG, stats2 + 4096);
    // final: out = x2 + affine2(AGG2)   (in-place on d_out)
    k_normF<<<1024, 256, 0, stream>>>((const float4*)AGG, XBh,
                                      stats2 + 4096, gammas + 2 * D_, betas + 2 * D_,
                                      (float4*)out);
}

// Round 10
// 292.866 us; speedup vs baseline: 1.7258x; 1.0368x over previous
//
#include <hip/hip_runtime.h>
#include <hip/hip_bf16.h>
#include <hip/hip_fp16.h>

#define N_ 50000
#define E_ 800000
#define D_ 128
#define L_ 3

#define GG 782            // gemm blocks: ceil(50000/64)
#define CB 3125           // count/fill blocks: E/256 exactly

typedef _Float16 half8 __attribute__((ext_vector_type(8)));
typedef float f32x4 __attribute__((ext_vector_type(4)));

// ---------------- helpers ----------------

__device__ inline float4 hcvt(uint2 u) {   // 4 packed fp16 -> float4
    __half2 h0 = *(__half2*)&u.x;
    __half2 h1 = *(__half2*)&u.y;
    float2 f0 = __half22float2(h0);
    float2 f1 = __half22float2(h1);
    return make_float4(f0.x, f0.y, f1.x, f1.y);
}

__device__ inline unsigned pkh(float a, float b) {  // 2 fp32 -> packed fp16 (RTNE)
    __half2 h = __floats2half2_rn(a, b);
    return *(unsigned*)&h;
}

__device__ inline unsigned short pkh1(float a) {
    _Float16 h = (_Float16)a;
    return *(unsigned short*)&h;
}

// ---------------- k_countw: edge count (+offset capture) fused with W transpose ----------------
// blocks [0, CB): count; blocks [CB, CB+3): transpose W layer (b-CB) fp32->fp16.

__global__ void k_countw(const int* __restrict__ dst, int* __restrict__ deg,
                         int* __restrict__ offbuf,
                         const float* __restrict__ Ws, unsigned short* __restrict__ Wb) {
    int b = blockIdx.x;
    if (b < CB) {
        int e = b * 256 + threadIdx.x;     // CB*256 == E_ exactly
        offbuf[e] = atomicAdd(&deg[dst[e]], 1);
    } else {
        int l = b - CB;                    // 0,1,2
        const float* Wl = Ws + l * 16384;
        unsigned short* Wo = Wb + l * 16384;
        for (int i = threadIdx.x; i < 16384; i += 256) {
            int n = i >> 7, k = i & 127;
            Wo[n * 128 + k] = pkh1(Wl[k * 128 + n]);
        }
    }
}

// ---------------- scans (verbatim round 8) ----------------

__global__ __launch_bounds__(1024) void k_scan1(const int* __restrict__ deg,
                                                int* __restrict__ linc,
                                                int* __restrict__ bsum,
                                                float* __restrict__ dis) {
    __shared__ int wsum[16];
    int t    = threadIdx.x;
    int lane = t & 63;
    int wid  = t >> 6;
    int i    = blockIdx.x * 1024 + t;
    int d    = (i < N_) ? deg[i] : 0;
    if (i < N_) dis[i] = rsqrtf((float)d + 1.0f);
    int v = d;
#pragma unroll
    for (int off = 1; off < 64; off <<= 1) {
        int u = __shfl_up(v, off);
        if (lane >= off) v += u;
    }
    if (lane == 63) wsum[wid] = v;
    __syncthreads();
    if (wid == 0) {
        int w = (lane < 16) ? wsum[lane] : 0;
#pragma unroll
        for (int off = 1; off < 16; off <<= 1) {
            int u = __shfl_up(w, off);
            if (lane >= off) w += u;
        }
        if (lane < 16) wsum[lane] = w;
    }
    __syncthreads();
    int woff = (wid > 0) ? wsum[wid - 1] : 0;
    v += woff;
    if (i < N_) linc[i] = v;
    if (t == 1023) bsum[blockIdx.x] = v;
}

__global__ __launch_bounds__(1024) void k_scan3(const int* __restrict__ linc,
                                                const int* __restrict__ bsum,
                                                int* __restrict__ row_ptr) {
    __shared__ int sboff;
    int t = threadIdx.x;
    if (t < 64) {
        int v = (t < 49) ? bsum[t] : 0;
#pragma unroll
        for (int off = 1; off < 64; off <<= 1) {
            int u = __shfl_up(v, off);
            if (t >= off) v += u;
        }
        int ex = (blockIdx.x == 0) ? 0 : __shfl(v, (int)blockIdx.x - 1, 64);
        if (t == 0) sboff = ex;
    }
    __syncthreads();
    int i = blockIdx.x * 1024 + t;
    if (i < N_) row_ptr[i + 1] = linc[i] + sboff;
    if (i == 0) row_ptr[0] = 0;
}

// ---------------- GEMM body (verbatim round 8, blk param) ----------------
// If st != null: x_row = relu(a*Xin + b) (+ resH fp16), side-written to xoutH (fp16);
// else x = Xin. Output: Hb = fp16( dis[row] * (x @ W) ), row-major [N][128].

__device__ __forceinline__ void gemm_body(const float* __restrict__ Xin,
                                          const unsigned short* __restrict__ Wb,
                                          const float* __restrict__ dis,
                                          uint4* __restrict__ Hb,
                                          const float* __restrict__ st,
                                          const float* __restrict__ gamma,
                                          const float* __restrict__ beta,
                                          const unsigned short* __restrict__ resH,
                                          unsigned short* __restrict__ xoutH,
                                          int blk) {
    __shared__ unsigned short wt[128 * 136];   // W^T fp16, padded stride 136
    __shared__ unsigned short xb[64 * 136];    // X tile fp16 (reused for C repack)
    __shared__ float sab[256];
    int t  = threadIdx.x;
    int r0 = blk * 64;

    if (st) {
        if (t < 128) {
            float s = 0.f, s2 = 0.f;
#pragma unroll
            for (int k = 0; k < 8; ++k) {
                s  += st[k * 256 + t];
                s2 += st[k * 256 + 128 + t];
            }
            float mean = s * (1.0f / N_);
            float var  = s2 * (1.0f / N_) - mean * mean;
            float a = gamma[t] * rsqrtf(var + 1e-5f);
            sab[t]       = a;
            sab[128 + t] = beta[t] - mean * a;
        }
        __syncthreads();
    }

    // stage W^T (2048 uint4, 8 per thread, coalesced)
#pragma unroll
    for (int j = 0; j < 8; ++j) {
        int i = t + 256 * j;
        int row = i >> 4, c16 = i & 15;
        *(uint4*)&wt[row * 136 + c16 * 8] = ((const uint4*)Wb)[i];
    }
    // stage X: fp32 -> (affine/relu/res) -> fp16 LDS (+ fp16 side-write)
#pragma unroll
    for (int j = 0; j < 8; ++j) {
        int g   = t + 256 * j;          // float4 index among 64*32
        int row = g >> 5;
        int c4  = (g & 31) * 4;
        int gr  = r0 + row;
        float4 v = make_float4(0.f, 0.f, 0.f, 0.f);
        if (gr < N_) {
            v = *(const float4*)(Xin + gr * 128 + c4);
            if (st) {
                v.x = fmaxf(sab[c4] * v.x + sab[128 + c4], 0.f);
                v.y = fmaxf(sab[c4 + 1] * v.y + sab[128 + c4 + 1], 0.f);
                v.z = fmaxf(sab[c4 + 2] * v.z + sab[128 + c4 + 2], 0.f);
                v.w = fmaxf(sab[c4 + 3] * v.w + sab[128 + c4 + 3], 0.f);
                if (resH) {
                    float4 rr = hcvt(*(const uint2*)(resH + gr * 128 + c4));
                    v.x += rr.x; v.y += rr.y; v.z += rr.z; v.w += rr.w;
                }
            }
        }
        uint2 p;
        p.x = pkh(v.x, v.y);
        p.y = pkh(v.z, v.w);
        if (st && gr < N_) *(uint2*)(xoutH + gr * 128 + c4) = p;
        *(uint2*)&xb[row * 136 + c4] = p;
    }
    __syncthreads();

    int wv   = t >> 6;
    int lane = t & 63;
    int ln   = lane & 15;
    int quad = lane >> 4;

    const unsigned short* arow = &xb[(wv * 16 + ln) * 136 + quad * 8];
    half8 af[4];
#pragma unroll
    for (int ks = 0; ks < 4; ++ks) af[ks] = *(const half8*)(arow + ks * 32);

    f32x4 acc[8];
#pragma unroll
    for (int ct = 0; ct < 8; ++ct) acc[ct] = (f32x4){0.f, 0.f, 0.f, 0.f};

#pragma unroll
    for (int ct = 0; ct < 8; ++ct) {
        const unsigned short* wp = &wt[(ct * 16 + ln) * 136 + quad * 8];
#pragma unroll
        for (int ks = 0; ks < 4; ++ks) {
            half8 bf = *(const half8*)(wp + ks * 32);
            acc[ct] = __builtin_amdgcn_mfma_f32_16x16x32_f16(af[ks], bf, acc[ct], 0, 0, 0);
        }
    }

    // epilogue: dis-scale, fp16, repack via LDS (xb reused), coalesced uint4 store
    float dr[4];
#pragma unroll
    for (int reg = 0; reg < 4; ++reg) {
        int r = r0 + wv * 16 + quad * 4 + reg;
        dr[reg] = dis[r < N_ ? r : (N_ - 1)];
    }
    __syncthreads();   // xb reuse
#pragma unroll
    for (int ct = 0; ct < 8; ++ct) {
#pragma unroll
        for (int reg = 0; reg < 4; ++reg) {
            int lrow = wv * 16 + quad * 4 + reg;
            xb[lrow * 136 + ct * 16 + ln] = pkh1(acc[ct][reg] * dr[reg]);
        }
    }
    __syncthreads();
#pragma unroll
    for (int j = 0; j < 4; ++j) {
        int i = t + 256 * j;       // uint4 among 64*16
        int row = i >> 4, c16 = i & 15;
        int gr = r0 + row;
        if (gr < N_) Hb[gr * 16 + c16] = *(uint4*)&xb[row * 136 + c16 * 8];
    }
}

// ---------------- k_fillg: layer-0 GEMM (blocks [0,GG)) + CSR fill (blocks [GG,GG+CB)) ----------------
// gemm blocks dispatched first so their MFMA work overlaps fill's latency-bound scatter.

__global__ __launch_bounds__(256) void k_fillg(const int* __restrict__ src,
                                               const int* __restrict__ dst,
                                               const int* __restrict__ row_ptr,
                                               const int* __restrict__ offbuf,
                                               int* __restrict__ csr_src,
                                               const float* __restrict__ x,
                                               const unsigned short* __restrict__ Wb,
                                               const float* __restrict__ dis,
                                               uint4* __restrict__ Hb) {
    int b = blockIdx.x;
    if (b < GG) {
        gemm_body(x, Wb, dis, Hb, nullptr, nullptr, nullptr, nullptr, nullptr, b);
    } else {
        int e = (b - GG) * 256 + threadIdx.x;   // CB*256 == E_ exactly
        int d = dst[e];
        csr_src[row_ptr[d] + offbuf[e]] = src[e];
    }
}

// ---------------- k_gemm: layers 1/2 ----------------

__global__ __launch_bounds__(256) void k_gemm(const float* __restrict__ Xin,
                                              const unsigned short* __restrict__ Wb,
                                              const float* __restrict__ dis,
                                              uint4* __restrict__ Hb,
                                              const float* __restrict__ st,
                                              const float* __restrict__ gamma,
                                              const float* __restrict__ beta,
                                              const unsigned short* __restrict__ resH,
                                              unsigned short* __restrict__ xoutH) {
    gemm_body(Xin, Wb, dis, Hb, st, gamma, beta, resH, xoutH, blockIdx.x);
}

// ---------------- Aggregation + fused BN stats (verbatim round 8) ----------------
// 16 nodes / 256-thread block (natural order); 16 lanes/node, 8 features (uint4) each.

__global__ __launch_bounds__(256) void k_agg(const uint4* __restrict__ Hb,
                                             const int* __restrict__ row_ptr,
                                             const int* __restrict__ csr_src,
                                             const float* __restrict__ dis,
                                             const float* __restrict__ bias,
                                             float4* __restrict__ AGG,
                                             float* __restrict__ stats2) {
    int tid  = threadIdx.x;
    int sub  = tid >> 4;          // 0..15 node in block
    int lane = tid & 15;          // feature group: 8 feats
    int node = blockIdx.x * 16 + sub;

    int beg = row_ptr[node], end = row_ptr[node + 1];
    uint4 su = Hb[node * 16 + lane];
    float4 acc0 = hcvt(make_uint2(su.x, su.y));
    float4 acc1 = hcvt(make_uint2(su.z, su.w));

    for (int c = beg; c < end; c += 16) {
        int m = end - c; if (m > 16) m = 16;
        int idx = (lane < m) ? csr_src[c + lane] : 0;
        int j = 0;
        for (; j + 4 <= m; j += 4) {
            int s0 = __shfl(idx, j, 16);
            int s1 = __shfl(idx, j + 1, 16);
            int s2 = __shfl(idx, j + 2, 16);
            int s3 = __shfl(idx, j + 3, 16);
            uint4 a0 = Hb[s0 * 16 + lane];
            uint4 a1 = Hb[s1 * 16 + lane];
            uint4 a2 = Hb[s2 * 16 + lane];
            uint4 a3 = Hb[s3 * 16 + lane];
            float4 f00 = hcvt(make_uint2(a0.x, a0.y)), f01 = hcvt(make_uint2(a0.z, a0.w));
            float4 f10 = hcvt(make_uint2(a1.x, a1.y)), f11 = hcvt(make_uint2(a1.z, a1.w));
            float4 f20 = hcvt(make_uint2(a2.x, a2.y)), f21 = hcvt(make_uint2(a2.z, a2.w));
            float4 f30 = hcvt(make_uint2(a3.x, a3.y)), f31 = hcvt(make_uint2(a3.z, a3.w));
            acc0.x += f00.x + f10.x + f20.x + f30.x;
            acc0.y += f00.y + f10.y + f20.y + f30.y;
            acc0.z += f00.z + f10.z + f20.z + f30.z;
            acc0.w += f00.w + f10.w + f20.w + f30.w;
            acc1.x += f01.x + f11.x + f21.x + f31.x;
            acc1.y += f01.y + f11.y + f21.y + f31.y;
            acc1.z += f01.z + f11.z + f21.z + f31.z;
            acc1.w += f01.w + f11.w + f21.w + f31.w;
        }
        for (; j < m; ++j) {
            int s0 = __shfl(idx, j, 16);
            uint4 a0 = Hb[s0 * 16 + lane];
            float4 f00 = hcvt(make_uint2(a0.x, a0.y)), f01 = hcvt(make_uint2(a0.z, a0.w));
            acc0.x += f00.x; acc0.y += f00.y; acc0.z += f00.z; acc0.w += f00.w;
            acc1.x += f01.x; acc1.y += f01.y; acc1.z += f01.z; acc1.w += f01.w;
        }
    }

    float dn = dis[node];
    float4 b0 = *(const float4*)(bias + lane * 8);
    float4 b1 = *(const float4*)(bias + lane * 8 + 4);
    float4 r0, r1;
    r0.x = dn * acc0.x + b0.x; r0.y = dn * acc0.y + b0.y;
    r0.z = dn * acc0.z + b0.z; r0.w = dn * acc0.w + b0.w;
    r1.x = dn * acc1.x + b1.x; r1.y = dn * acc1.y + b1.y;
    r1.z = dn * acc1.z + b1.z; r1.w = dn * acc1.w + b1.w;
    AGG[node * 32 + lane * 2]     = r0;
    AGG[node * 32 + lane * 2 + 1] = r1;

    __shared__ float sbuf[16][128];
    float4* sp = (float4*)&sbuf[sub][lane * 8];
    sp[0] = r0; sp[1] = r1;
    __syncthreads();
    if (tid < 128) {
        float s = 0.f, s2 = 0.f;
#pragma unroll
        for (int k = 0; k < 16; ++k) {
            float v = sbuf[k][tid];
            s += v; s2 += v * v;
        }
        float* stp = stats2 + (blockIdx.x & 7) * 256;
        atomicAdd(&stp[tid], s);
        atomicAdd(&stp[128 + tid], s2);
    }
}

// ---------------- Final normalize (layer 2): out = resH + affine(AGG) ----------------

__global__ __launch_bounds__(256) void k_normF(const float4* __restrict__ AGG,
                                               const unsigned short* __restrict__ resH,
                                               const float* __restrict__ st,
                                               const float* __restrict__ gamma,
                                               const float* __restrict__ beta,
                                               float4* __restrict__ OUT) {
    __shared__ float sab[256];
    int t = threadIdx.x;
    if (t < 128) {
        float s = 0.f, s2 = 0.f;
#pragma unroll
        for (int k = 0; k < 8; ++k) {
            s  += st[k * 256 + t];
            s2 += st[k * 256 + 128 + t];
        }
        float mean = s * (1.0f / N_);
        float var  = s2 * (1.0f / N_) - mean * mean;
        float a = gamma[t] * rsqrtf(var + 1e-5f);
        sab[t]       = a;
        sab[128 + t] = beta[t] - mean * a;
    }
    __syncthreads();
    for (int i = blockIdx.x * 256 + t; i < N_ * 32; i += gridDim.x * 256) {
        int f4 = (i & 31) * 4;
        float4 v = AGG[i];
        float4 rr = hcvt(((const uint2*)resH)[i]);
        v.x = sab[f4] * v.x + sab[128 + f4] + rr.x;
        v.y = sab[f4 + 1] * v.y + sab[128 + f4 + 1] + rr.y;
        v.z = sab[f4 + 2] * v.z + sab[128 + f4 + 2] + rr.z;
        v.w = sab[f4 + 3] * v.w + sab[128 + f4 + 3] + rr.w;
        OUT[i] = v;
    }
}

// ---------------- Launch ----------------

extern "C" void kernel_launch(void* const* d_in, const int* in_sizes, int n_in,
                              void* d_out, int out_size, void* d_ws, size_t ws_size,
                              hipStream_t stream) {
    const float* x      = (const float*)d_in[0];
    const int*   ei     = (const int*)d_in[1];
    const float* Ws     = (const float*)d_in[2];
    const float* bs     = (const float*)d_in[3];
    const float* gammas = (const float*)d_in[4];
    const float* betas  = (const float*)d_in[5];
    float* out = (float*)d_out;

    const int* src = ei;
    const int* dst = ei + E_;

    char* w = (char*)d_ws;
    int*   deg     = (int*)(w + 0);            // N ints            [0, 200000)
    float* stats2  = (float*)(w + 200000);     // 3*2048 floats     [200000, 224576)
    int*   row_ptr = (int*)(w + 224576);       // N+1 ints          [224576, 424580)
    float* dis     = (float*)(w + 424592);     // N floats          [424592, 624592)
    int*   offbuf  = (int*)(w + 624592);       // E ints            [624592, 3824592)
    int*   csr_src = (int*)(w + 3824592);      // E ints            [3824592, 7024592)
    uint4* Hb      = (uint4*)(w + 7024640);    // N*D fp16 12.8 MB  [7024640, 19824640)
    unsigned short* XBh = (unsigned short*)(w + 19824640);  // N*D fp16 [19824640, 32624640)
    unsigned short* Wb  = (unsigned short*)(w + 32624640);  // 3*16384 fp16 [32624640, 32722944)
    float* AGG     = out;                      // AGG lives in d_out

    // scan scratch reuses XBh (dead until gemm1 writes it)
    int* linc = (int*)XBh;          // N ints
    int* bsum = (int*)XBh + N_;     // 49 ints

    hipMemsetAsync(d_ws, 0, 224576, stream);   // deg + stats2

    // count (+offset capture) fused with W fp16-transpose (3 extra blocks)
    k_countw<<<CB + 3, 256, 0, stream>>>(dst, deg, offbuf, Ws, Wb);
    k_scan1<<<49, 1024, 0, stream>>>(deg, linc, bsum, dis);
    k_scan3<<<49, 1024, 0, stream>>>(linc, bsum, row_ptr);
    // layer-0 GEMM (needs dis, ready) fused with CSR fill (needs row_ptr, ready)
    k_fillg<<<GG + CB, 256, 0, stream>>>(src, dst, row_ptr, offbuf, csr_src,
                                         x, Wb, dis, Hb);

    // L0: agg -> AGG(d_out), st0
    k_agg<<<N_ / 16, 256, 0, stream>>>(Hb, row_ptr, csr_src, dis, bs,
                                       (float4*)AGG, stats2);
    // L1: gemm(AGG0 | affine0+relu -> XBh) -> Hb ; agg -> AGG, st1
    k_gemm<<<GG, 256, 0, stream>>>(AGG, Wb + 16384, dis, Hb,
                                   stats2, gammas, betas, nullptr, XBh);
    k_agg<<<N_ / 16, 256, 0, stream>>>(Hb, row_ptr, csr_src, dis, bs + D_,
                                       (float4*)AGG, stats2 + 2048);
    // L2: gemm(AGG1 | affine1+relu + res XBh -> XBh) -> Hb ; agg -> AGG, st2
    k_gemm<<<GG, 256, 0, stream>>>(AGG, Wb + 32768, dis, Hb,
                                   stats2 + 2048, gammas + D_, betas + D_, XBh, XBh);
    k_agg<<<N_ / 16, 256, 0, stream>>>(Hb, row_ptr, csr_src, dis, bs + 2 * D_,
                                       (float4*)AGG, stats2 + 4096);
    // final: out = x2 + affine2(AGG2)   (in-place on d_out)
    k_normF<<<1024, 256, 0, stream>>>((const float4*)AGG, XBh,
                                      stats2 + 4096, gammas + 2 * D_, betas + 2 * D_,
                                      (float4*)out);
}